// Round 6
// baseline (4488.847 us; speedup 1.0000x reference)
//
#include <hip/hip_runtime.h>

// Teacher-forced GRU + additive attention decoder, MI355X. FLOAT32 I/O.
// Round 15: R13 tagged-slot protocol (fastest measured: 2650us) + replicate-dec.
// R14 post-mortem: separating detection (sentinel) from data read added one
// full LLC latency per hop -> slower despite less traffic. R13's "data is the
// flag" is right. This round removes the hop-A Dacc exchange entirely:
// W_dec (128x256) is replicated into registers (32 u32 x 512 thr); each block
// computes full dec locally from gathered h. Effects: h published ~150cy
// earlier; hop-A detect becomes poll1 (1 slot) instead of gather8 (8-slot
// AND, worst tail); 1024 tagged slots/batch-step deleted. Cost: ~200cy local
// dot + 1 barrier (6/step total).
#define BB    32
#define TDEC  400
#define TENC  800
#define EDIM  256
#define GDIM  256
#define ADIM  128
#define IDIM  80
#define G3    768
#define NSL   8     // slices (blocks) per batch element
#define SLH   32    // GDIM/NSL h-elements per slice
#define SLT   100   // TENC/NSL encoder timesteps per slice
#define XCST  257   // XcpS per-block slot count (256 e + 1 wsum)
#define EPST  136   // encp LDS row stride (u16), 16B aligned
#define ETST  102   // enc_t LDS row stride (u16): 51 u32/row

typedef unsigned short u16;
typedef unsigned int u32;
typedef unsigned long long u64;

__device__ __forceinline__ float b2f(u16 u) {
  union { u32 i; float f; } x; x.i = ((u32)u) << 16; return x.f;
}
__device__ __forceinline__ u16 f2b(float f) {
  union { float f; u32 u; } x; x.f = f;
  u32 u = x.u; u += 0x7fffu + ((u >> 16) & 1u);
  return (u16)(u >> 16);
}
__device__ __forceinline__ void ld8(const u16* p, float* w) {
  const uint4 q = *reinterpret_cast<const uint4*>(p);
  union { u32 i; float f; } c;
  c.i = q.x << 16;          w[0] = c.f;
  c.i = q.x & 0xffff0000u;  w[1] = c.f;
  c.i = q.y << 16;          w[2] = c.f;
  c.i = q.y & 0xffff0000u;  w[3] = c.f;
  c.i = q.z << 16;          w[4] = c.f;
  c.i = q.z & 0xffff0000u;  w[5] = c.f;
  c.i = q.w << 16;          w[6] = c.f;
  c.i = q.w & 0xffff0000u;  w[7] = c.f;
}
__device__ __forceinline__ void ldf8(const float* p, float* w) {
  const float4 a = *reinterpret_cast<const float4*>(p);
  const float4 b = *reinterpret_cast<const float4*>(p + 4);
  w[0] = a.x; w[1] = a.y; w[2] = a.z; w[3] = a.w;
  w[4] = b.x; w[5] = b.y; w[6] = b.z; w[7] = b.w;
}
__device__ __forceinline__ float fsigmoid(float x) {
  return __builtin_amdgcn_rcpf(1.f + __expf(-x));
}
__device__ __forceinline__ float ftanh(float x) {
  float e = __expf(2.f * x);
  return 1.f - 2.f * __builtin_amdgcn_rcpf(e + 1.f);
}
// ---- epoch-tagged 8B slots (agent scope, relaxed) ----
__device__ __forceinline__ void pst(float2* p, float v, u32 tag) {
  union { u64 u; u32 w[2]; } pk;
  pk.w[0] = __float_as_uint(v); pk.w[1] = tag;
  __hip_atomic_store((u64*)p, pk.u, __ATOMIC_RELAXED, __HIP_MEMORY_SCOPE_AGENT);
}
__device__ __forceinline__ u64 pld(const float2* p) {
  return __hip_atomic_load((const u64*)p, __ATOMIC_RELAXED,
                           __HIP_MEMORY_SCOPE_AGENT);
}
// poll one slot until tag matches, return value
__device__ __forceinline__ float poll1(const float2* p, u32 tag) {
  for (;;) {
    const u64 x = pld(p);
    if ((u32)(x >> 32) == tag) return __uint_as_float((u32)x);
    __builtin_amdgcn_s_sleep(1);
  }
}
// poll 8 strided slots until all tags match, return sum of values + init
__device__ __forceinline__ float gather8(const float2* base, int stride,
                                         u32 tag, float init) {
  u64 x[8];
  for (;;) {
    bool ok = true;
    #pragma unroll
    for (int k = 0; k < 8; ++k) x[k] = pld(base + (size_t)k * stride);
    #pragma unroll
    for (int k = 0; k < 8; ++k) ok &= ((u32)(x[k] >> 32) == tag);
    if (ok) break;
    __builtin_amdgcn_s_sleep(1);
  }
  float s = init;
  #pragma unroll
  for (int k = 0; k < 8; ++k) s += __uint_as_float((u32)x[k]);
  return s;
}

// ---------------- K1: gi_x[b][t][g] = x_t . W_ih[:, :80] + b_ih (bf16 out) -----
__global__ __launch_bounds__(256) void k_gix(
    const float* __restrict__ gt, const float* __restrict__ W_ih,
    const float* __restrict__ b_ih, u16* __restrict__ gi_x) {
  __shared__ float sc_x[8][IDIM];
  const int tid = threadIdx.x;
  const int b = blockIdx.x / 50;
  const int t0 = (blockIdx.x % 50) * 8;
  for (int idx = tid; idx < 8 * IDIM; idx += 256) {
    int row = idx / IDIM, col = idx % IDIM;
    sc_x[row][col] = gt[((size_t)b * TDEC + t0 + row) * IDIM + col];
  }
  __syncthreads();
  for (int kk = 0; kk < 3; ++kk) {
    const int g = tid + 256 * kk;
    const float* wrow = W_ih + (size_t)g * 336;
    float acc[8] = {0,0,0,0,0,0,0,0};
    #pragma unroll 2
    for (int k8 = 0; k8 < IDIM / 8; ++k8) {
      float w[8]; ldf8(wrow + (k8 << 3), w);
      #pragma unroll
      for (int tt = 0; tt < 8; ++tt) {
        const float* x = &sc_x[tt][k8 << 3];
        acc[tt] += w[0]*x[0] + w[1]*x[1] + w[2]*x[2] + w[3]*x[3]
                 + w[4]*x[4] + w[5]*x[5] + w[6]*x[6] + w[7]*x[7];
      }
    }
    const float bias = b_ih[g];
    #pragma unroll
    for (int tt = 0; tt < 8; ++tt)
      gi_x[((size_t)b * TDEC + t0 + tt) * G3 + g] = f2b(acc[tt] + bias);
  }
}

// ------- K2: enc_proj (bf16) + bf16 copy of enc_feat ---------------------------
__global__ __launch_bounds__(256) void k_encp(
    const float* __restrict__ enc_feat, const float* __restrict__ W_enc,
    u16* __restrict__ encp, u16* __restrict__ enc_bf) {
  __shared__ float sc_x[16][EDIM];
  const int tid = threadIdx.x;
  const int b = blockIdx.x / 50;
  const int te0 = (blockIdx.x % 50) * 16;
  for (int idx = tid; idx < 16 * EDIM; idx += 256) {
    int row = idx >> 8, col = idx & 255;
    sc_x[row][col] = enc_feat[((size_t)b * TENC + te0 + row) * EDIM + col];
  }
  __syncthreads();
  const int a = tid & 127;
  const int tg = tid >> 7;
  const float* wrow = W_enc + (size_t)a * EDIM;
  float acc[8] = {0,0,0,0,0,0,0,0};
  #pragma unroll 4
  for (int k8 = 0; k8 < EDIM / 8; ++k8) {
    float w[8]; ldf8(wrow + (k8 << 3), w);
    #pragma unroll
    for (int tt = 0; tt < 8; ++tt) {
      const float* x = &sc_x[tg * 8 + tt][k8 << 3];
      acc[tt] += w[0]*x[0] + w[1]*x[1] + w[2]*x[2] + w[3]*x[3]
               + w[4]*x[4] + w[5]*x[5] + w[6]*x[6] + w[7]*x[7];
    }
  }
  #pragma unroll
  for (int tt = 0; tt < 8; ++tt)
    encp[((size_t)b * TENC + te0 + tg * 8 + tt) * ADIM + a] = f2b(acc[tt]);
  for (int idx = tid; idx < 16 * EDIM; idx += 256)
    enc_bf[((size_t)b * TENC + te0) * EDIM + idx] = f2b(sc_x[idx >> 8][idx & 255]);
}

// ---------------- K3: persistent step loop (8 blocks x 512 thr per batch) ------
__global__ __launch_bounds__(512, 1) void k_decode(
    const float* __restrict__ W_ih, const float* __restrict__ W_hh,
    const float* __restrict__ b_hh, const float* __restrict__ W_dec,
    const float* __restrict__ b_attn, const float* __restrict__ v_attn,
    const u16* __restrict__ gi_x, const u16* __restrict__ encp,
    const u16* __restrict__ enc_bf, float* __restrict__ stash,
    float2* __restrict__ XhS, float2* __restrict__ XcpS,
    float* __restrict__ out_attn) {
  extern __shared__ __align__(16) u16 dynlds[];
  u16* encp_lds = dynlds;              // SLT*EPST = 13600 u16 = 27200 B
  u16* enc_t    = dynlds + SLT * EPST; // EDIM*ETST = 26112 u16 = 52224 B [e][te]

  __shared__ __align__(16) float sc_h[256];          // h(t)
  __shared__ float sc_ing[4][68];   // ctx quarters, stride 68 (conflict-free)
  __shared__ float sc_inh[4][68];   // h quarters
  __shared__ float sc_dec[ADIM];
  __shared__ float sc_g0[96];   // W_ihc.ctx + gi_x
  __shared__ float sc_g1[96];   // W_hh.h + b_hh (shadow-computed)
  __shared__ float sc_w[104];
  __shared__ float sc_v[ADIM];
  __shared__ float sc_ba[ADIM];
  __shared__ float sc_bhh[96];
  __shared__ float sc_gx[96];
  __shared__ float sc_S;

  const int tid = threadIdx.x;
  const int b = blockIdx.x & 31;
  const int j = blockIdx.x >> 5;      // 0..7
  const int lane = tid & 63;

  // ---- one-time: gate weights -> registers (quad-split rows, 96 rows) ----
  u32 wctx[32], whh[32];
  #pragma unroll
  for (int i = 0; i < 32; ++i) { wctx[i] = 0u; whh[i] = 0u; }
  if (tid < 384) {
    const int r = tid >> 2, q = tid & 3;
    const int grow = (r >> 5) * 256 + SLH * j + (r & 31);
    const float2* s1 = reinterpret_cast<const float2*>(
        W_ih + (size_t)grow * 336 + 80 + q * 64);
    const float2* s2 = reinterpret_cast<const float2*>(
        W_hh + (size_t)grow * 256 + q * 64);
    #pragma unroll
    for (int i = 0; i < 32; ++i) {
      const float2 v1 = s1[i], v2 = s2[i];
      wctx[i] = (u32)f2b(v1.x) | ((u32)f2b(v1.y) << 16);
      whh[i]  = (u32)f2b(v2.x) | ((u32)f2b(v2.y) << 16);
    }
  }
  // ---- one-time: W_dec fully replicated -> registers (row a, quarter q) ----
  u32 wdec[32];
  {
    const int a = tid >> 2, q = tid & 3;
    const float2* s3 = reinterpret_cast<const float2*>(
        W_dec + (size_t)a * GDIM + q * 64);
    #pragma unroll
    for (int i = 0; i < 32; ++i) {
      const float2 v = s3[i];
      wdec[i] = (u32)f2b(v.x) | ((u32)f2b(v.y) << 16);
    }
  }
  // ---- one-time LDS preloads ----
  for (int idx = tid; idx < SLT * ADIM; idx += 512) {
    const int te = idx >> 7, a = idx & 127;
    encp_lds[te * EPST + a] = encp[((size_t)b * TENC + SLT * j + te) * ADIM + a];
  }
  for (int idx = tid; idx < SLT * EDIM; idx += 512) {
    const int te = idx >> 8, e = idx & 255;
    enc_t[e * ETST + te] = enc_bf[((size_t)b * TENC + SLT * j + te) * EDIM + e];
  }
  if (tid < ADIM) { sc_v[tid] = v_attn[tid]; sc_ba[tid] = b_attn[tid]; }
  if (tid < 96) {
    const int grow = (tid >> 5) * 256 + SLH * j + (tid & 31);
    const float bh = b_hh[grow];
    sc_bhh[tid] = bh;
    sc_g1[tid] = bh;                                   // gh(h=0) = b_hh
    sc_gx[tid] = b2f(gi_x[((size_t)b * TDEC + 0) * G3 + grow]);
  }
  if (tid < 256) {
    sc_h[tid] = 0.f;
    sc_ing[tid >> 6][tid & 63] = 0.f;
    sc_inh[tid >> 6][tid & 63] = 0.f;
  }
  float hprev = 0.f;   // own h-slice element (wave0, lane<SLH), reg-resident
  __syncthreads();

  for (int t = 0; t < TDEC; ++t) {
    const u32 tag = (u32)(t + 1);
    // -------- G0: ctx-half gate dots (register weights, strided LDS) ---------
    if (tid < 384) {
      const float* act = &sc_ing[tid & 3][0];
      float acc = 0.f;
      #pragma unroll
      for (int i = 0; i < 32; ++i) {
        union { u32 u; float f; } lo, hi;
        lo.u = wctx[i] << 16; hi.u = wctx[i] & 0xffff0000u;
        acc += lo.f * act[2 * i] + hi.f * act[2 * i + 1];
      }
      acc += __shfl_xor(acc, 1);
      acc += __shfl_xor(acc, 2);
      if ((tid & 3) == 0) sc_g0[tid >> 2] = acc + sc_gx[tid >> 2];
    }
    __syncthreads();  // B1: sc_g0 ready (sc_g1 from prev step's shadow)
    // -------- hop A: wave0 publishes h-slice ASAP; 256 pollers; prefetch -----
    if (tid < 64) {
      if (lane < SLH) {
        const float gr = sc_g0[lane] + sc_g1[lane];
        const float gz = sc_g0[SLH + lane] + sc_g1[SLH + lane];
        const float rr = fsigmoid(gr);
        const float zz = fsigmoid(gz);
        const float nn = ftanh(sc_g0[2 * SLH + lane] + rr * sc_g1[2 * SLH + lane]);
        const float hval = (1.f - zz) * nn + zz * hprev;
        hprev = hval;
        pst(&XhS[b * GDIM + SLH * j + lane], hval, tag);
      }
    } else if (tid < 320) {
      const int g = tid - 64;
      const float hv = poll1(&XhS[b * GDIM + g], tag);
      sc_h[g] = hv;
      sc_inh[g >> 6][g & 63] = hv;
    } else if (tid < 416) {  // prefetch gi_x(t+1) (sc_gx consumed at B1)
      const int tn = (t + 1 < TDEC) ? t + 1 : t;
      const int gl = tid - 320;
      const int grow = (gl >> 5) * 256 + SLH * j + (gl & 31);
      sc_gx[gl] = b2f(gi_x[((size_t)b * TDEC + tn) * G3 + grow]);
    }
    __syncthreads();  // B2: full h(t) in LDS
    // -------- replicated dec: every block computes full W_dec.h + b_attn -----
    {
      const int a = tid >> 2, q = tid & 3;
      const float* hp = &sc_inh[q][0];
      float acc = 0.f;
      #pragma unroll
      for (int i = 0; i < 32; ++i) {
        union { u32 u; float f; } lo, hi;
        lo.u = wdec[i] << 16; hi.u = wdec[i] & 0xffff0000u;
        acc += lo.f * hp[2 * i] + hi.f * hp[2 * i + 1];
      }
      acc += __shfl_xor(acc, 1);
      acc += __shfl_xor(acc, 2);
      if (q == 0) sc_dec[a] = acc + sc_ba[a];
    }
    __syncthreads();  // B3: sc_dec ready
    // -------- scores (tid<400) | stash-h (400-447, j==0) ---------------------
    if (tid < 400) {
      const int te = tid >> 2, q4 = tid & 3;
      const u16* ep = &encp_lds[te * EPST + q4 * 32];
      const float* dp = sc_dec + q4 * 32;
      const float* vp = sc_v + q4 * 32;
      float s = 0.f;
      #pragma unroll
      for (int k8 = 0; k8 < 4; ++k8) {
        float w[8]; ld8(ep + (k8 << 3), w);
        #pragma unroll
        for (int i = 0; i < 8; ++i) {
          const int a = (k8 << 3) + i;
          s += ftanh(w[i] + dp[a]) * vp[a];
        }
      }
      s += __shfl_xor(s, 1);
      s += __shfl_xor(s, 2);
      if (q4 == 0) sc_w[te] = __expf(s);  // |s| <= ||v||_1 ~ 5: max-free safe
    } else if (tid < 448) {
      if (j == 0) {
        for (int g = tid - 400; g < 256; g += 48)
          stash[((size_t)b * TDEC + t) * 512 + g] = sc_h[g];
      }
    }
    __syncthreads();  // B4: sc_w ready
    // -------- hop B: publish cp+wsum; shadow gh; gather ----------------------
    if (tid < 256) {
      const u32* et = reinterpret_cast<const u32*>(&enc_t[tid * ETST]);
      float pc = 0.f;
      #pragma unroll
      for (int k2 = 0; k2 < 50; ++k2) {
        const u32 w2 = et[k2];
        union { u32 u; float f; } lo, hi;
        lo.u = w2 << 16; hi.u = w2 & 0xffff0000u;
        pc += sc_w[2 * k2] * lo.f + sc_w[2 * k2 + 1] * hi.f;
      }
      pst(&XcpS[(b * NSL + j) * XCST + tid], pc, tag);
    }
    if (tid < 64) {
      float v = (lane < 50) ? sc_w[lane] + sc_w[lane + 50] : 0.f;
      #pragma unroll
      for (int off = 1; off < 64; off <<= 1) v += __shfl_xor(v, off);
      if (lane == 0) pst(&XcpS[(b * NSL + j) * XCST + 256], v, tag);
    }
    // shadow: gh(t) = W_hh.h(t) + b_hh, overlaps slot propagation
    if (tid < 384) {
      const float* act = &sc_inh[tid & 3][0];
      float acc = 0.f;
      #pragma unroll
      for (int i = 0; i < 32; ++i) {
        union { u32 u; float f; } lo, hi;
        lo.u = whh[i] << 16; hi.u = whh[i] & 0xffff0000u;
        acc += lo.f * act[2 * i] + hi.f * act[2 * i + 1];
      }
      acc += __shfl_xor(acc, 1);
      acc += __shfl_xor(acc, 2);
      if ((tid & 3) == 0) sc_g1[tid >> 2] = acc + sc_bhh[tid >> 2];
    }
    float csum = 0.f;
    if (tid < 256) {
      csum = gather8(&XcpS[b * NSL * XCST + tid], XCST, tag, 0.f);
    } else if (tid == 256) {
      sc_S = gather8(&XcpS[b * NSL * XCST + 256], XCST, tag, 0.f);
    }
    __syncthreads();  // B5: csum in regs, sc_S + sc_g1 ready
    // -------- epilogue -------------------------------------------------------
    {
      const float invS = __builtin_amdgcn_rcpf(sc_S);
      if (tid < 256) {
        const float cv = csum * invS;
        sc_ing[tid >> 6][tid & 63] = cv;  // ctx(t) for next-step gates
        if (j == 0) stash[((size_t)b * TDEC + t) * 512 + 256 + tid] = cv;
      }
      if (tid < SLT)
        out_attn[((size_t)b * TDEC + t) * TENC + SLT * j + tid] =
            sc_w[tid] * invS;
    }
    __syncthreads();  // B6
  }
}

// ---------------- K4: pred = log_softmax([h;ctx] . W_out^T + b_out) ------------
__global__ __launch_bounds__(256) void k_pred(
    const float* __restrict__ stash, const float* __restrict__ W_out,
    const float* __restrict__ b_out, float* __restrict__ out_pred) {
  __shared__ float sc_s[4][512];
  __shared__ float sc_lp[2][4][IDIM];
  __shared__ float sc_l[4][IDIM];
  __shared__ float sc_lse[4];
  const int tid = threadIdx.x;
  const int b = blockIdx.x / 100;
  const int t0 = (blockIdx.x % 100) * 4;
  for (int idx = tid; idx < 4 * 512; idx += 256)
    sc_s[idx >> 9][idx & 511] = stash[((size_t)b * TDEC + t0) * 512 + idx];
  __syncthreads();
  const int o = tid & 127, kh = tid >> 7;
  if (o < IDIM) {
    const float* wrow = W_out + (size_t)o * 512 + kh * 256;
    float acc[4] = {0,0,0,0};
    #pragma unroll 4
    for (int k8 = 0; k8 < 32; ++k8) {
      float w[8]; ldf8(wrow + (k8 << 3), w);
      #pragma unroll
      for (int tt = 0; tt < 4; ++tt) {
        const float* x = &sc_s[tt][kh * 256 + (k8 << 3)];
        acc[tt] += w[0]*x[0] + w[1]*x[1] + w[2]*x[2] + w[3]*x[3]
                 + w[4]*x[4] + w[5]*x[5] + w[6]*x[6] + w[7]*x[7];
      }
    }
    #pragma unroll
    for (int tt = 0; tt < 4; ++tt) sc_lp[kh][tt][o] = acc[tt];
  }
  __syncthreads();
  if (tid < IDIM) {
    const float bb = b_out[tid];
    #pragma unroll
    for (int tt = 0; tt < 4; ++tt)
      sc_l[tt][tid] = sc_lp[0][tt][tid] + sc_lp[1][tt][tid] + bb;
  }
  __syncthreads();
  {
    const int w = tid >> 6, lane = tid & 63;
    const float a0 = sc_l[w][lane];
    const float a1 = (lane < IDIM - 64) ? sc_l[w][lane + 64] : -1e30f;
    float m = fmaxf(a0, a1);
    #pragma unroll
    for (int off = 1; off < 64; off <<= 1) m = fmaxf(m, __shfl_xor(m, off));
    float e = __expf(a0 - m) + ((lane < IDIM - 64) ? __expf(a1 - m) : 0.f);
    #pragma unroll
    for (int off = 1; off < 64; off <<= 1) e += __shfl_xor(e, off);
    if (lane == 0) sc_lse[w] = m + __logf(e);
  }
  __syncthreads();
  for (int idx = tid; idx < 4 * IDIM; idx += 256) {
    const int tt = idx / IDIM, oo = idx % IDIM;
    out_pred[((size_t)b * TDEC + t0 + tt) * IDIM + oo] =
        sc_l[tt][oo] - sc_lse[tt];
  }
}

extern "C" void kernel_launch(void* const* d_in, const int* in_sizes, int n_in,
                              void* d_out, int out_size, void* d_ws, size_t ws_size,
                              hipStream_t stream) {
  const float* enc_feat = (const float*)d_in[0];
  const float* gt       = (const float*)d_in[1];
  const float* W_ih     = (const float*)d_in[2];
  const float* W_hh     = (const float*)d_in[3];
  const float* b_ih     = (const float*)d_in[4];
  const float* b_hh     = (const float*)d_in[5];
  const float* W_enc    = (const float*)d_in[6];
  const float* W_dec    = (const float*)d_in[7];
  const float* b_attn   = (const float*)d_in[8];
  const float* v_attn   = (const float*)d_in[9];
  const float* W_out    = (const float*)d_in[10];
  const float* b_out    = (const float*)d_in[11];
  float* out_pred = (float*)d_out;
  float* out_attn = out_pred + (size_t)BB * TDEC * IDIM;

  char* ws = (char*)d_ws;
  size_t off = 0;
  u16* gi_x   = (u16*)(ws + off);   off += (size_t)BB * TDEC * G3 * 2;
  u16* encp   = (u16*)(ws + off);   off += (size_t)BB * TENC * ADIM * 2;
  u16* enc_bf = (u16*)(ws + off);   off += (size_t)BB * TENC * EDIM * 2;
  float* stash= (float*)(ws + off); off += (size_t)BB * TDEC * 512 * 4;
  // ---- zeroed region (one memset): tagged slot arrays (tags start at 0) ----
  char* zbase = ws + off;
  float2* XhS   = (float2*)(ws + off); off += (size_t)BB * GDIM * 8;
  float2* XcpS  = (float2*)(ws + off); off += (size_t)BB * NSL * XCST * 8;
  const size_t zbytes = (size_t)(ws + off - zbase);

  // dynamic LDS for k_decode: encp slice + transposed enc slice
  const int DYNB = (SLT * EPST + EDIM * ETST) * 2;  // 79424 B
  static bool s_attr = false;
  if (!s_attr) {
    (void)hipFuncSetAttribute(reinterpret_cast<const void*>(k_decode),
                              hipFuncAttributeMaxDynamicSharedMemorySize, DYNB);
    s_attr = true;
  }

  hipMemsetAsync(zbase, 0, zbytes, stream);

  hipLaunchKernelGGL(k_gix, dim3(BB * 50), dim3(256), 0, stream,
                     gt, W_ih, b_ih, gi_x);
  hipLaunchKernelGGL(k_encp, dim3(BB * 50), dim3(256), 0, stream,
                     enc_feat, W_enc, encp, enc_bf);
  hipLaunchKernelGGL(k_decode, dim3(BB * NSL), dim3(512), DYNB, stream,
                     W_ih, W_hh, b_hh, W_dec, b_attn, v_attn,
                     gi_x, encp, enc_bf, stash, XhS, XcpS, out_attn);
  hipLaunchKernelGGL(k_pred, dim3(BB * 100), dim3(256), 0, stream,
                     stash, W_out, b_out, out_pred);
}

// Round 7
// 2790.200 us; speedup vs baseline: 1.6088x; 1.6088x over previous
//
#include <hip/hip_runtime.h>

// Teacher-forced GRU + additive attention decoder, MI355X. FLOAT32 I/O.
// Round 16: exact R13 structure (best measured: 2650us k_decode) with ONE
// change: tagged slots carry bf16 PAIRS ({2x bf16, u32 tag} per 8B packet)
// instead of {f32, tag}. Halves slot counts (h 32->16/block, Dacc 128->64,
// cp 256->128) and poll-loop LLC load traffic (hop A 1280->832/round, hop B
// 2048->1032). R13 FETCH=235MB was poll re-reads saturating the LLC atomic
// path; this attacks that without changing the proven rendezvous structure.
// f32 kept for: recurrence state hprev, all final sums, wsum slot, sc_w.
#define BB    32
#define TDEC  400
#define TENC  800
#define EDIM  256
#define GDIM  256
#define ADIM  128
#define IDIM  80
#define G3    768
#define NSL   8     // slices (blocks) per batch element
#define SLH   32    // GDIM/NSL h-elements per slice
#define SLT   100   // TENC/NSL encoder timesteps per slice
#define XCP2  129   // XcpS per-block slots (128 cp pairs + 1 f32 wsum)
#define EPST  136   // encp LDS row stride (u16), 16B aligned
#define ETST  102   // enc_t LDS row stride (u16): 51 u32/row

typedef unsigned short u16;
typedef unsigned int u32;
typedef unsigned long long u64;

__device__ __forceinline__ float b2f(u16 u) {
  union { u32 i; float f; } x; x.i = ((u32)u) << 16; return x.f;
}
__device__ __forceinline__ u16 f2b(float f) {
  union { float f; u32 u; } x; x.f = f;
  u32 u = x.u; u += 0x7fffu + ((u >> 16) & 1u);
  return (u16)(u >> 16);
}
__device__ __forceinline__ void ld8(const u16* p, float* w) {
  const uint4 q = *reinterpret_cast<const uint4*>(p);
  union { u32 i; float f; } c;
  c.i = q.x << 16;          w[0] = c.f;
  c.i = q.x & 0xffff0000u;  w[1] = c.f;
  c.i = q.y << 16;          w[2] = c.f;
  c.i = q.y & 0xffff0000u;  w[3] = c.f;
  c.i = q.z << 16;          w[4] = c.f;
  c.i = q.z & 0xffff0000u;  w[5] = c.f;
  c.i = q.w << 16;          w[6] = c.f;
  c.i = q.w & 0xffff0000u;  w[7] = c.f;
}
__device__ __forceinline__ void ldf8(const float* p, float* w) {
  const float4 a = *reinterpret_cast<const float4*>(p);
  const float4 b = *reinterpret_cast<const float4*>(p + 4);
  w[0] = a.x; w[1] = a.y; w[2] = a.z; w[3] = a.w;
  w[4] = b.x; w[5] = b.y; w[6] = b.z; w[7] = b.w;
}
__device__ __forceinline__ float fsigmoid(float x) {
  return __builtin_amdgcn_rcpf(1.f + __expf(-x));
}
__device__ __forceinline__ float ftanh(float x) {
  float e = __expf(2.f * x);
  return 1.f - 2.f * __builtin_amdgcn_rcpf(e + 1.f);
}
// ---- epoch-tagged 8B slots (agent scope, relaxed) ----
__device__ __forceinline__ void pst(float2* p, float v, u32 tag) {
  union { u64 u; u32 w[2]; } pk;
  pk.w[0] = __float_as_uint(v); pk.w[1] = tag;
  __hip_atomic_store((u64*)p, pk.u, __ATOMIC_RELAXED, __HIP_MEMORY_SCOPE_AGENT);
}
// bf16-pair packet: {lo bf16, hi bf16, tag}
__device__ __forceinline__ void pstp(float2* p, float lo, float hi, u32 tag) {
  union { u64 u; u32 w[2]; } pk;
  pk.w[0] = (u32)f2b(lo) | ((u32)f2b(hi) << 16);
  pk.w[1] = tag;
  __hip_atomic_store((u64*)p, pk.u, __ATOMIC_RELAXED, __HIP_MEMORY_SCOPE_AGENT);
}
__device__ __forceinline__ u64 pld(const float2* p) {
  return __hip_atomic_load((const u64*)p, __ATOMIC_RELAXED,
                           __HIP_MEMORY_SCOPE_AGENT);
}
// poll one pair-slot until tag matches, return packed bf16 pair
__device__ __forceinline__ u32 poll1p(const float2* p, u32 tag) {
  for (;;) {
    const u64 x = pld(p);
    if ((u32)(x >> 32) == tag) return (u32)x;
    __builtin_amdgcn_s_sleep(1);
  }
}
// poll 8 strided f32 slots until all tags match, return sum + init
__device__ __forceinline__ float gather8(const float2* base, int stride,
                                         u32 tag, float init) {
  u64 x[8];
  for (;;) {
    bool ok = true;
    #pragma unroll
    for (int k = 0; k < 8; ++k) x[k] = pld(base + (size_t)k * stride);
    #pragma unroll
    for (int k = 0; k < 8; ++k) ok &= ((u32)(x[k] >> 32) == tag);
    if (ok) break;
    __builtin_amdgcn_s_sleep(1);
  }
  float s = init;
  #pragma unroll
  for (int k = 0; k < 8; ++k) s += __uint_as_float((u32)x[k]);
  return s;
}
// poll 8 strided pair-slots until all match, return f32 sums of lo/hi
__device__ __forceinline__ float2 gather8p(const float2* base, int stride,
                                           u32 tag) {
  u64 x[8];
  for (;;) {
    bool ok = true;
    #pragma unroll
    for (int k = 0; k < 8; ++k) x[k] = pld(base + (size_t)k * stride);
    #pragma unroll
    for (int k = 0; k < 8; ++k) ok &= ((u32)(x[k] >> 32) == tag);
    if (ok) break;
    __builtin_amdgcn_s_sleep(1);
  }
  float lo = 0.f, hi = 0.f;
  #pragma unroll
  for (int k = 0; k < 8; ++k) {
    lo += b2f((u16)x[k]);
    hi += b2f((u16)(x[k] >> 16));
  }
  return make_float2(lo, hi);
}

// ---------------- K1: gi_x[b][t][g] = x_t . W_ih[:, :80] + b_ih (bf16 out) -----
__global__ __launch_bounds__(256) void k_gix(
    const float* __restrict__ gt, const float* __restrict__ W_ih,
    const float* __restrict__ b_ih, u16* __restrict__ gi_x) {
  __shared__ float sc_x[8][IDIM];
  const int tid = threadIdx.x;
  const int b = blockIdx.x / 50;
  const int t0 = (blockIdx.x % 50) * 8;
  for (int idx = tid; idx < 8 * IDIM; idx += 256) {
    int row = idx / IDIM, col = idx % IDIM;
    sc_x[row][col] = gt[((size_t)b * TDEC + t0 + row) * IDIM + col];
  }
  __syncthreads();
  for (int kk = 0; kk < 3; ++kk) {
    const int g = tid + 256 * kk;
    const float* wrow = W_ih + (size_t)g * 336;
    float acc[8] = {0,0,0,0,0,0,0,0};
    #pragma unroll 2
    for (int k8 = 0; k8 < IDIM / 8; ++k8) {
      float w[8]; ldf8(wrow + (k8 << 3), w);
      #pragma unroll
      for (int tt = 0; tt < 8; ++tt) {
        const float* x = &sc_x[tt][k8 << 3];
        acc[tt] += w[0]*x[0] + w[1]*x[1] + w[2]*x[2] + w[3]*x[3]
                 + w[4]*x[4] + w[5]*x[5] + w[6]*x[6] + w[7]*x[7];
      }
    }
    const float bias = b_ih[g];
    #pragma unroll
    for (int tt = 0; tt < 8; ++tt)
      gi_x[((size_t)b * TDEC + t0 + tt) * G3 + g] = f2b(acc[tt] + bias);
  }
}

// ------- K2: enc_proj (bf16) + bf16 copy of enc_feat ---------------------------
__global__ __launch_bounds__(256) void k_encp(
    const float* __restrict__ enc_feat, const float* __restrict__ W_enc,
    u16* __restrict__ encp, u16* __restrict__ enc_bf) {
  __shared__ float sc_x[16][EDIM];
  const int tid = threadIdx.x;
  const int b = blockIdx.x / 50;
  const int te0 = (blockIdx.x % 50) * 16;
  for (int idx = tid; idx < 16 * EDIM; idx += 256) {
    int row = idx >> 8, col = idx & 255;
    sc_x[row][col] = enc_feat[((size_t)b * TENC + te0 + row) * EDIM + col];
  }
  __syncthreads();
  const int a = tid & 127;
  const int tg = tid >> 7;
  const float* wrow = W_enc + (size_t)a * EDIM;
  float acc[8] = {0,0,0,0,0,0,0,0};
  #pragma unroll 4
  for (int k8 = 0; k8 < EDIM / 8; ++k8) {
    float w[8]; ldf8(wrow + (k8 << 3), w);
    #pragma unroll
    for (int tt = 0; tt < 8; ++tt) {
      const float* x = &sc_x[tg * 8 + tt][k8 << 3];
      acc[tt] += w[0]*x[0] + w[1]*x[1] + w[2]*x[2] + w[3]*x[3]
               + w[4]*x[4] + w[5]*x[5] + w[6]*x[6] + w[7]*x[7];
    }
  }
  #pragma unroll
  for (int tt = 0; tt < 8; ++tt)
    encp[((size_t)b * TENC + te0 + tg * 8 + tt) * ADIM + a] = f2b(acc[tt]);
  for (int idx = tid; idx < 16 * EDIM; idx += 256)
    enc_bf[((size_t)b * TENC + te0) * EDIM + idx] = f2b(sc_x[idx >> 8][idx & 255]);
}

// ---------------- K3: persistent step loop (8 blocks x 512 thr per batch) ------
__global__ __launch_bounds__(512, 1) void k_decode(
    const float* __restrict__ W_ih, const float* __restrict__ W_hh,
    const float* __restrict__ b_hh, const float* __restrict__ W_dec,
    const float* __restrict__ b_attn, const float* __restrict__ v_attn,
    const u16* __restrict__ gi_x, const u16* __restrict__ encp,
    const u16* __restrict__ enc_bf, float* __restrict__ stash,
    float2* __restrict__ XhS, float2* __restrict__ DaccS,
    float2* __restrict__ XcpS, float* __restrict__ out_attn) {
  extern __shared__ __align__(16) u16 dynlds[];
  u16* encp_lds = dynlds;              // SLT*EPST = 13600 u16 = 27200 B
  u16* enc_t    = dynlds + SLT * EPST; // EDIM*ETST = 26112 u16 = 52224 B [e][te]

  __shared__ u32 sWdp[ADIM * 17];                    // 8704 B, W_dec[:,slice]
  __shared__ __align__(16) float sc_h[256];          // h(t)
  __shared__ float sc_ing[4][68];   // ctx quarters, stride 68 (conflict-free)
  __shared__ float sc_inh[4][68];   // h quarters
  __shared__ float sc_dec[ADIM];
  __shared__ float sc_g0[96];   // W_ihc.ctx + gi_x
  __shared__ float sc_g1[96];   // W_hh.h + b_hh (shadow-computed)
  __shared__ float sc_w[104];
  __shared__ float sc_v[ADIM];
  __shared__ float sc_ba[ADIM];
  __shared__ float sc_bhh[96];
  __shared__ float sc_gx[96];
  __shared__ float sc_S;

  const int tid = threadIdx.x;
  const int b = blockIdx.x & 31;
  const int j = blockIdx.x >> 5;      // 0..7
  const int lane = tid & 63;

  // ---- one-time: gate weights -> registers (quad-split rows, 96 rows) ----
  u32 wctx[32], whh[32];
  #pragma unroll
  for (int i = 0; i < 32; ++i) { wctx[i] = 0u; whh[i] = 0u; }
  if (tid < 384) {
    const int r = tid >> 2, q = tid & 3;
    const int grow = (r >> 5) * 256 + SLH * j + (r & 31);
    const float2* s1 = reinterpret_cast<const float2*>(
        W_ih + (size_t)grow * 336 + 80 + q * 64);
    const float2* s2 = reinterpret_cast<const float2*>(
        W_hh + (size_t)grow * 256 + q * 64);
    #pragma unroll
    for (int i = 0; i < 32; ++i) {
      const float2 v1 = s1[i], v2 = s2[i];
      wctx[i] = (u32)f2b(v1.x) | ((u32)f2b(v1.y) << 16);
      whh[i]  = (u32)f2b(v2.x) | ((u32)f2b(v2.y) << 16);
    }
  }
  // ---- one-time LDS preloads ----
  for (int idx = tid; idx < ADIM * 16; idx += 512) {  // W_dec[:, 32-col slice]
    const int a = idx >> 4, k2 = idx & 15;
    const float2 v = *reinterpret_cast<const float2*>(
        W_dec + (size_t)a * GDIM + SLH * j + 2 * k2);
    sWdp[a * 17 + k2] = (u32)f2b(v.x) | ((u32)f2b(v.y) << 16);
  }
  for (int idx = tid; idx < SLT * ADIM; idx += 512) {
    const int te = idx >> 7, a = idx & 127;
    encp_lds[te * EPST + a] = encp[((size_t)b * TENC + SLT * j + te) * ADIM + a];
  }
  for (int idx = tid; idx < SLT * EDIM; idx += 512) {
    const int te = idx >> 8, e = idx & 255;
    enc_t[e * ETST + te] = enc_bf[((size_t)b * TENC + SLT * j + te) * EDIM + e];
  }
  if (tid < ADIM) { sc_v[tid] = v_attn[tid]; sc_ba[tid] = b_attn[tid]; }
  if (tid < 96) {
    const int grow = (tid >> 5) * 256 + SLH * j + (tid & 31);
    const float bh = b_hh[grow];
    sc_bhh[tid] = bh;
    sc_g1[tid] = bh;                                   // gh(h=0) = b_hh
    sc_gx[tid] = b2f(gi_x[((size_t)b * TDEC + 0) * G3 + grow]);
  }
  if (tid < 256) {
    sc_h[tid] = 0.f;
    sc_ing[tid >> 6][tid & 63] = 0.f;
    sc_inh[tid >> 6][tid & 63] = 0.f;
  }
  float hprev = 0.f;   // own h-slice element (wave0, lane<SLH), reg-resident
  __syncthreads();

  for (int t = 0; t < TDEC; ++t) {
    const u32 tag = (u32)(t + 1);
    // -------- G0: ctx-half gate dots (register weights, strided LDS) ---------
    if (tid < 384) {
      const float* act = &sc_ing[tid & 3][0];
      float acc = 0.f;
      #pragma unroll
      for (int i = 0; i < 32; ++i) {
        union { u32 u; float f; } lo, hi;
        lo.u = wctx[i] << 16; hi.u = wctx[i] & 0xffff0000u;
        acc += lo.f * act[2 * i] + hi.f * act[2 * i + 1];
      }
      acc += __shfl_xor(acc, 1);
      acc += __shfl_xor(acc, 2);
      if ((tid & 3) == 0) sc_g0[tid >> 2] = acc + sc_gx[tid >> 2];
    }
    __syncthreads();  // B1: sc_g0 ready (sc_g1 from prev step's shadow)
    // -------- hop A: wave0 publish h+dec pairs | 128 poll h | 64 gather dec --
    if (tid < 64) {
      float hval = 0.f;
      if (lane < SLH) {
        const float gr = sc_g0[lane] + sc_g1[lane];
        const float gz = sc_g0[SLH + lane] + sc_g1[SLH + lane];
        const float rr = fsigmoid(gr);
        const float zz = fsigmoid(gz);
        const float nn = ftanh(sc_g0[2 * SLH + lane] + rr * sc_g1[2 * SLH + lane]);
        hval = (1.f - zz) * nn + zz * hprev;
        hprev = hval;
      }
      const float hx = __shfl(hval, lane ^ 1);
      if (lane < SLH && (lane & 1) == 0)
        pstp(&XhS[b * 128 + 16 * j + (lane >> 1)], hval, hx, tag);
      float hn[32];
      #pragma unroll
      for (int k = 0; k < 32; ++k) hn[k] = __shfl(hval, k);
      float accs[2];
      #pragma unroll
      for (int r2 = 0; r2 < 2; ++r2) {
        const int a = lane + 64 * r2;
        const u32* wp = &sWdp[a * 17];
        float acc = 0.f;
        #pragma unroll
        for (int k2 = 0; k2 < 16; ++k2) {
          const u32 w2 = wp[k2];
          union { u32 u; float f; } lo, hi;
          lo.u = w2 << 16; hi.u = w2 & 0xffff0000u;
          acc += lo.f * hn[2 * k2] + hi.f * hn[2 * k2 + 1];
        }
        accs[r2] = acc;
      }
      pstp(&DaccS[(b * NSL + j) * 64 + lane], accs[0], accs[1], tag);
    } else if (tid < 192) {  // 128 pollers: h pairs
      const int g2 = tid - 64;
      const u32 hp = poll1p(&XhS[b * 128 + g2], tag);
      const float h0 = b2f((u16)hp), h1 = b2f((u16)(hp >> 16));
      const int g = 2 * g2, q = g >> 6, r = g & 63;
      sc_h[g] = h0; sc_h[g + 1] = h1;
      sc_inh[q][r] = h0; sc_inh[q][r + 1] = h1;
    } else if (tid < 256) {  // 64 gatherers: dec pairs
      const int l = tid - 192;
      const float2 d = gather8p(&DaccS[b * NSL * 64 + l], 64, tag);
      sc_dec[l] = d.x + sc_ba[l];
      sc_dec[l + 64] = d.y + sc_ba[l + 64];
    }
    __syncthreads();  // B4: sc_dec + full h in LDS
    // -------- scores (tid<400) | stash-h (400-447, j==0) | prefetch (448+) ---
    if (tid < 400) {
      const int te = tid >> 2, q4 = tid & 3;
      const u16* ep = &encp_lds[te * EPST + q4 * 32];
      const float* dp = sc_dec + q4 * 32;
      const float* vp = sc_v + q4 * 32;
      float s = 0.f;
      #pragma unroll
      for (int k8 = 0; k8 < 4; ++k8) {
        float w[8]; ld8(ep + (k8 << 3), w);
        #pragma unroll
        for (int i = 0; i < 8; ++i) {
          const int a = (k8 << 3) + i;
          s += ftanh(w[i] + dp[a]) * vp[a];
        }
      }
      s += __shfl_xor(s, 1);
      s += __shfl_xor(s, 2);
      if (q4 == 0) sc_w[te] = __expf(s);  // |s| <= ||v||_1 ~ 5: max-free safe
    } else if (tid < 448) {
      if (j == 0) {
        for (int g = tid - 400; g < 256; g += 48)
          stash[((size_t)b * TDEC + t) * 512 + g] = sc_h[g];
      }
    } else {  // wave7: prefetch gi_x(t+1)
      const int tn = (t + 1 < TDEC) ? t + 1 : t;
      const int gl = tid - 448;
      {
        const int grow = (gl >> 5) * 256 + SLH * j + (gl & 31);
        sc_gx[gl] = b2f(gi_x[((size_t)b * TDEC + tn) * G3 + grow]);
      }
      if (gl < 32) {
        const int g2 = gl + 64;
        const int grow = (g2 >> 5) * 256 + SLH * j + (g2 & 31);
        sc_gx[g2] = b2f(gi_x[((size_t)b * TDEC + tn) * G3 + grow]);
      }
    }
    __syncthreads();  // B5: sc_w ready
    // -------- hop B: publish cp pairs + wsum; shadow gh; gather --------------
    if (tid < 256) {
      const u32* et = reinterpret_cast<const u32*>(&enc_t[tid * ETST]);
      float pc = 0.f;
      #pragma unroll
      for (int k2 = 0; k2 < 50; ++k2) {
        const u32 w2 = et[k2];
        union { u32 u; float f; } lo, hi;
        lo.u = w2 << 16; hi.u = w2 & 0xffff0000u;
        pc += sc_w[2 * k2] * lo.f + sc_w[2 * k2 + 1] * hi.f;
      }
      const float pc2 = __shfl_xor(pc, 1);
      if ((tid & 1) == 0)
        pstp(&XcpS[(b * NSL + j) * XCP2 + (tid >> 1)], pc, pc2, tag);
    }
    if (tid < 64) {
      float v = (lane < 50) ? sc_w[lane] + sc_w[lane + 50] : 0.f;
      #pragma unroll
      for (int off = 1; off < 64; off <<= 1) v += __shfl_xor(v, off);
      if (lane == 0) pst(&XcpS[(b * NSL + j) * XCP2 + 128], v, tag);
    }
    // shadow: gh(t) = W_hh.h(t) + b_hh, overlaps slot propagation
    if (tid < 384) {
      const float* act = &sc_inh[tid & 3][0];
      float acc = 0.f;
      #pragma unroll
      for (int i = 0; i < 32; ++i) {
        union { u32 u; float f; } lo, hi;
        lo.u = whh[i] << 16; hi.u = whh[i] & 0xffff0000u;
        acc += lo.f * act[2 * i] + hi.f * act[2 * i + 1];
      }
      acc += __shfl_xor(acc, 1);
      acc += __shfl_xor(acc, 2);
      if ((tid & 3) == 0) sc_g1[tid >> 2] = acc + sc_bhh[tid >> 2];
    }
    float2 csum = make_float2(0.f, 0.f);
    if (tid < 128) {
      csum = gather8p(&XcpS[b * NSL * XCP2 + tid], XCP2, tag);
    } else if (tid == 128) {
      sc_S = gather8(&XcpS[b * NSL * XCP2 + 128], XCP2, tag, 0.f);
    }
    __syncthreads();  // B7: csum in regs, sc_S + sc_g1 ready
    // -------- epilogue -------------------------------------------------------
    {
      const float invS = __builtin_amdgcn_rcpf(sc_S);
      if (tid < 128) {
        const float cv0 = csum.x * invS, cv1 = csum.y * invS;
        const int e = 2 * tid, q = e >> 6, r = e & 63;
        sc_ing[q][r] = cv0; sc_ing[q][r + 1] = cv1;
        if (j == 0) {
          stash[((size_t)b * TDEC + t) * 512 + 256 + e] = cv0;
          stash[((size_t)b * TDEC + t) * 512 + 256 + e + 1] = cv1;
        }
      }
      if (tid < SLT)
        out_attn[((size_t)b * TDEC + t) * TENC + SLT * j + tid] =
            sc_w[tid] * invS;
    }
    __syncthreads();  // B8
  }
}

// ---------------- K4: pred = log_softmax([h;ctx] . W_out^T + b_out) ------------
__global__ __launch_bounds__(256) void k_pred(
    const float* __restrict__ stash, const float* __restrict__ W_out,
    const float* __restrict__ b_out, float* __restrict__ out_pred) {
  __shared__ float sc_s[4][512];
  __shared__ float sc_lp[2][4][IDIM];
  __shared__ float sc_l[4][IDIM];
  __shared__ float sc_lse[4];
  const int tid = threadIdx.x;
  const int b = blockIdx.x / 100;
  const int t0 = (blockIdx.x % 100) * 4;
  for (int idx = tid; idx < 4 * 512; idx += 256)
    sc_s[idx >> 9][idx & 511] = stash[((size_t)b * TDEC + t0) * 512 + idx];
  __syncthreads();
  const int o = tid & 127, kh = tid >> 7;
  if (o < IDIM) {
    const float* wrow = W_out + (size_t)o * 512 + kh * 256;
    float acc[4] = {0,0,0,0};
    #pragma unroll 4
    for (int k8 = 0; k8 < 32; ++k8) {
      float w[8]; ldf8(wrow + (k8 << 3), w);
      #pragma unroll
      for (int tt = 0; tt < 4; ++tt) {
        const float* x = &sc_s[tt][kh * 256 + (k8 << 3)];
        acc[tt] += w[0]*x[0] + w[1]*x[1] + w[2]*x[2] + w[3]*x[3]
                 + w[4]*x[4] + w[5]*x[5] + w[6]*x[6] + w[7]*x[7];
      }
    }
    #pragma unroll
    for (int tt = 0; tt < 4; ++tt) sc_lp[kh][tt][o] = acc[tt];
  }
  __syncthreads();
  if (tid < IDIM) {
    const float bb = b_out[tid];
    #pragma unroll
    for (int tt = 0; tt < 4; ++tt)
      sc_l[tt][tid] = sc_lp[0][tt][tid] + sc_lp[1][tt][tid] + bb;
  }
  __syncthreads();
  {
    const int w = tid >> 6, lane = tid & 63;
    const float a0 = sc_l[w][lane];
    const float a1 = (lane < IDIM - 64) ? sc_l[w][lane + 64] : -1e30f;
    float m = fmaxf(a0, a1);
    #pragma unroll
    for (int off = 1; off < 64; off <<= 1) m = fmaxf(m, __shfl_xor(m, off));
    float e = __expf(a0 - m) + ((lane < IDIM - 64) ? __expf(a1 - m) : 0.f);
    #pragma unroll
    for (int off = 1; off < 64; off <<= 1) e += __shfl_xor(e, off);
    if (lane == 0) sc_lse[w] = m + __logf(e);
  }
  __syncthreads();
  for (int idx = tid; idx < 4 * IDIM; idx += 256) {
    const int tt = idx / IDIM, oo = idx % IDIM;
    out_pred[((size_t)b * TDEC + t0 + tt) * IDIM + oo] =
        sc_l[tt][oo] - sc_lse[tt];
  }
}

extern "C" void kernel_launch(void* const* d_in, const int* in_sizes, int n_in,
                              void* d_out, int out_size, void* d_ws, size_t ws_size,
                              hipStream_t stream) {
  const float* enc_feat = (const float*)d_in[0];
  const float* gt       = (const float*)d_in[1];
  const float* W_ih     = (const float*)d_in[2];
  const float* W_hh     = (const float*)d_in[3];
  const float* b_ih     = (const float*)d_in[4];
  const float* b_hh     = (const float*)d_in[5];
  const float* W_enc    = (const float*)d_in[6];
  const float* W_dec    = (const float*)d_in[7];
  const float* b_attn   = (const float*)d_in[8];
  const float* v_attn   = (const float*)d_in[9];
  const float* W_out    = (const float*)d_in[10];
  const float* b_out    = (const float*)d_in[11];
  float* out_pred = (float*)d_out;
  float* out_attn = out_pred + (size_t)BB * TDEC * IDIM;

  char* ws = (char*)d_ws;
  size_t off = 0;
  u16* gi_x   = (u16*)(ws + off);   off += (size_t)BB * TDEC * G3 * 2;
  u16* encp   = (u16*)(ws + off);   off += (size_t)BB * TENC * ADIM * 2;
  u16* enc_bf = (u16*)(ws + off);   off += (size_t)BB * TENC * EDIM * 2;
  float* stash= (float*)(ws + off); off += (size_t)BB * TDEC * 512 * 4;
  // ---- zeroed region (one memset): tagged slot arrays (tags start at 0) ----
  char* zbase = ws + off;
  float2* XhS   = (float2*)(ws + off); off += (size_t)BB * 128 * 8;
  float2* DaccS = (float2*)(ws + off); off += (size_t)BB * NSL * 64 * 8;
  float2* XcpS  = (float2*)(ws + off); off += (size_t)BB * NSL * XCP2 * 8;
  const size_t zbytes = (size_t)(ws + off - zbase);

  // dynamic LDS for k_decode: encp slice + transposed enc slice
  const int DYNB = (SLT * EPST + EDIM * ETST) * 2;  // 79424 B
  static bool s_attr = false;
  if (!s_attr) {
    (void)hipFuncSetAttribute(reinterpret_cast<const void*>(k_decode),
                              hipFuncAttributeMaxDynamicSharedMemorySize, DYNB);
    s_attr = true;
  }

  hipMemsetAsync(zbase, 0, zbytes, stream);

  hipLaunchKernelGGL(k_gix, dim3(BB * 50), dim3(256), 0, stream,
                     gt, W_ih, b_ih, gi_x);
  hipLaunchKernelGGL(k_encp, dim3(BB * 50), dim3(256), 0, stream,
                     enc_feat, W_enc, encp, enc_bf);
  hipLaunchKernelGGL(k_decode, dim3(BB * NSL), dim3(512), DYNB, stream,
                     W_ih, W_hh, b_hh, W_dec, b_attn, v_attn,
                     gi_x, encp, enc_bf, stash, XhS, DaccS, XcpS, out_attn);
  hipLaunchKernelGGL(k_pred, dim3(BB * 100), dim3(256), 0, stream,
                     stash, W_out, b_out, out_pred);
}